// Round 1
// baseline (1772.246 us; speedup 1.0000x reference)
//
#include <hip/hip_runtime.h>

#define NN 100000
#define NE 3200000
#define INCH 256
#define HIDF 64

// ---------------------------------------------------------------------------
// edge dtype sniffer: if edge_index is int64 (values < 2^17), every odd u32
// word is 0. If int32, 256 consecutive odd words all-zero is ~impossible.
// ---------------------------------------------------------------------------
__global__ void detect_i64(const unsigned int* __restrict__ ei, int* __restrict__ flag) {
    __shared__ int nonzero;
    if (threadIdx.x == 0) nonzero = 0;
    __syncthreads();
    if (ei[2 * (size_t)threadIdx.x + 1] != 0u) nonzero = 1;
    __syncthreads();
    if (threadIdx.x == 0) *flag = (nonzero == 0) ? 1 : 0;
}

__device__ __forceinline__ int edge_at(const void* ei, int is64, long long i) {
    if (is64) return (int)((const long long*)ei)[i];
    return ((const int*)ei)[i];
}

// ---------------------------------------------------------------------------
// degree / normalization
// ---------------------------------------------------------------------------
__global__ void deg_init(float* __restrict__ deg, int n) {
    int i = blockIdx.x * blockDim.x + threadIdx.x;
    if (i < n) deg[i] = 1.0f;   // self-loop contributes 1
}

__global__ void deg_accum(const void* __restrict__ ei, const int* __restrict__ flag,
                          float* __restrict__ deg, int E) {
    int is64 = *flag;
    long long stride = (long long)gridDim.x * blockDim.x;
    for (long long e = (long long)blockIdx.x * blockDim.x + threadIdx.x; e < E; e += stride) {
        int d = edge_at(ei, is64, (long long)E + e);
        atomicAdd(&deg[d], 1.0f);
    }
}

__global__ void deg_to_dinv(float* __restrict__ deg, int n) {
    int i = blockIdx.x * blockDim.x + threadIdx.x;
    if (i < n) {
        float d = deg[i];
        deg[i] = (d > 0.f) ? rsqrtf(d) : 0.f;
    }
}

// ---------------------------------------------------------------------------
// GEMM: Y[N][64] = X[N][K] @ W[K][64], K in {256, 64}
// block 256 threads, tile = 128 rows x 64 cols, thread = 8 rows x 4 cols
// xs stride 65 -> conflict-free scalar reads (rows differ by 8 across lanes)
// ---------------------------------------------------------------------------
template <int K>
__global__ __launch_bounds__(256) void gemm_k64(const float* __restrict__ X,
                                                const float* __restrict__ W,
                                                float* __restrict__ Y, int n) {
    __shared__ float xs[128 * 65];
    __shared__ float ws[64 * 64];
    const int t  = threadIdx.x;
    const int r0 = blockIdx.x * 128;
    const int tc = t & 15;   // col group: cols tc*4 .. tc*4+3
    const int tr = t >> 4;   // row group: rows tr*8 .. tr*8+7

    float acc[8][4];
#pragma unroll
    for (int i = 0; i < 8; i++)
#pragma unroll
        for (int j = 0; j < 4; j++) acc[i][j] = 0.f;

    for (int kc = 0; kc < K; kc += 64) {
        // stage W chunk: 64x64 floats, coalesced float4
#pragma unroll
        for (int i = 0; i < 4; i++) {
            int off = (i * 256 + t) * 4;
            *(float4*)&ws[off] = *(const float4*)&W[(size_t)kc * 64 + off];
        }
        // stage X chunk: 128 rows x 64 cols
#pragma unroll
        for (int i = 0; i < 8; i++) {
            int linear = i * 256 + t;
            int row = linear >> 4;
            int k4  = linear & 15;
            float4 v = {0.f, 0.f, 0.f, 0.f};
            int gr = r0 + row;
            if (gr < n) v = *(const float4*)&X[(size_t)gr * K + kc + k4 * 4];
            int base = row * 65 + k4 * 4;
            xs[base + 0] = v.x;
            xs[base + 1] = v.y;
            xs[base + 2] = v.z;
            xs[base + 3] = v.w;
        }
        __syncthreads();

#pragma unroll 4
        for (int k = 0; k < 64; k++) {
            float4 wv = *(const float4*)&ws[k * 64 + tc * 4];
#pragma unroll
            for (int i = 0; i < 8; i++) {
                float xv = xs[(tr * 8 + i) * 65 + k];
                acc[i][0] += xv * wv.x;
                acc[i][1] += xv * wv.y;
                acc[i][2] += xv * wv.z;
                acc[i][3] += xv * wv.w;
            }
        }
        __syncthreads();
    }

#pragma unroll
    for (int i = 0; i < 8; i++) {
        int gr = r0 + tr * 8 + i;
        if (gr < n) {
            float4 o = {acc[i][0], acc[i][1], acc[i][2], acc[i][3]};
            *(float4*)&Y[(size_t)gr * 64 + tc * 4] = o;
        }
    }
}

// ---------------------------------------------------------------------------
// edge scatter: agg[dst] += hw[src] * dinv[src]*dinv[dst]   (one wave / edge)
// ---------------------------------------------------------------------------
__global__ void scatter_edges(const float* __restrict__ hw, const void* __restrict__ ei,
                              const int* __restrict__ flag, const float* __restrict__ dinv,
                              float* __restrict__ agg, int E) {
    int is64 = *flag;
    int lane = threadIdx.x & 63;
    long long wave   = ((long long)blockIdx.x * blockDim.x + threadIdx.x) >> 6;
    long long nwaves = ((long long)gridDim.x * blockDim.x) >> 6;
    for (long long e = wave; e < E; e += nwaves) {
        int s = edge_at(ei, is64, e);
        int d = edge_at(ei, is64, (long long)E + e);
        float nrm = dinv[s] * dinv[d];
        float v = hw[(size_t)s * 64 + lane] * nrm;
        atomicAdd(&agg[(size_t)d * 64 + lane], v);
    }
}

// ---------------------------------------------------------------------------
// h = relu(agg + hw*dinv^2 + b)   (adds self-loop message + bias, in place)
// ---------------------------------------------------------------------------
__global__ void finalize_relu(float* __restrict__ h, const float* __restrict__ hw,
                              const float* __restrict__ dinv, const float* __restrict__ b,
                              int n) {
    long long total  = (long long)n * 64;
    long long stride = (long long)gridDim.x * blockDim.x;
    for (long long i = (long long)blockIdx.x * blockDim.x + threadIdx.x; i < total; i += stride) {
        int node = (int)(i >> 6);
        int f    = (int)(i & 63);
        float di = dinv[node];
        float v  = h[i] + hw[i] * di * di + b[f];
        h[i] = fmaxf(v, 0.f);
    }
}

// ---------------------------------------------------------------------------
// fused MLP head: out = relu(h @ Wh1 + bh1) @ Wh2 + bh2
// block 128 threads, one row per thread, row staged in LDS (stride 65)
// ---------------------------------------------------------------------------
__global__ __launch_bounds__(128) void head_kernel(const float* __restrict__ h,
                                                   const float* __restrict__ Wh1,
                                                   const float* __restrict__ bh1,
                                                   const float* __restrict__ Wh2,
                                                   const float* __restrict__ bh2,
                                                   float* __restrict__ out, int n) {
    __shared__ float xs[128 * 65];
    __shared__ float w1s[64 * 32];
    __shared__ float w2s[64];
    __shared__ float b1s[32];
    __shared__ float b2s[2];
    const int t  = threadIdx.x;
    const int r0 = blockIdx.x * 128;

#pragma unroll
    for (int i = 0; i < 4; i++) {     // 64*32 = 2048 floats
        int off = (i * 128 + t) * 4;
        *(float4*)&w1s[off] = *(const float4*)&Wh1[off];
    }
    if (t < 64) w2s[t] = Wh2[t];
    if (t < 32) b1s[t] = bh1[t];
    if (t < 2)  b2s[t] = bh2[t];

#pragma unroll
    for (int i = 0; i < 16; i++) {    // 128 rows x 64 cols
        int linear = i * 128 + t;
        int row = linear >> 4;
        int k4  = linear & 15;
        float4 v = {0.f, 0.f, 0.f, 0.f};
        int gr = r0 + row;
        if (gr < n) v = *(const float4*)&h[(size_t)gr * 64 + k4 * 4];
        int base = row * 65 + k4 * 4;
        xs[base + 0] = v.x;
        xs[base + 1] = v.y;
        xs[base + 2] = v.z;
        xs[base + 3] = v.w;
    }
    __syncthreads();

    float hid[32];
#pragma unroll
    for (int j = 0; j < 32; j++) hid[j] = b1s[j];

#pragma unroll 4
    for (int k = 0; k < 64; k++) {
        float xv = xs[t * 65 + k];
#pragma unroll
        for (int j4 = 0; j4 < 8; j4++) {
            float4 w = *(const float4*)&w1s[k * 32 + j4 * 4];
            hid[j4 * 4 + 0] += xv * w.x;
            hid[j4 * 4 + 1] += xv * w.y;
            hid[j4 * 4 + 2] += xv * w.z;
            hid[j4 * 4 + 3] += xv * w.w;
        }
    }

    float o0 = b2s[0], o1 = b2s[1];
#pragma unroll
    for (int j = 0; j < 32; j++) {
        float hv = fmaxf(hid[j], 0.f);
        o0 += hv * w2s[j * 2 + 0];
        o1 += hv * w2s[j * 2 + 1];
    }
    int gr = r0 + t;
    if (gr < n) {
        out[(size_t)gr * 2 + 0] = o0;
        out[(size_t)gr * 2 + 1] = o1;
    }
}

// ---------------------------------------------------------------------------
extern "C" void kernel_launch(void* const* d_in, const int* in_sizes, int n_in,
                              void* d_out, int out_size, void* d_ws, size_t ws_size,
                              hipStream_t stream) {
    const float* x   = (const float*)d_in[0];
    const void*  ei  = d_in[1];
    const float* W1  = (const float*)d_in[2];
    const float* b1  = (const float*)d_in[3];
    const float* W2  = (const float*)d_in[4];
    const float* b2  = (const float*)d_in[5];
    const float* Wh1 = (const float*)d_in[6];
    const float* bh1 = (const float*)d_in[7];
    const float* Wh2 = (const float*)d_in[8];
    const float* bh2 = (const float*)d_in[9];
    float* out = (float*)d_out;

    const int n = in_sizes[0] / INCH;   // 100000
    const int E = in_sizes[1] / 2;      // 3200000

    // workspace layout (256B-aligned slabs)
    char* ws = (char*)d_ws;
    size_t off = 0;
    auto carve = [&](size_t bytes) {
        size_t p = off;
        off = (off + bytes + 255) & ~(size_t)255;
        return p;
    };
    int*   flag = (int*)(ws + carve(256));
    float* dinv = (float*)(ws + carve((size_t)n * 4));          // deg -> dinv in place
    float* bufA = (float*)(ws + carve((size_t)n * HIDF * 4));   // hw (pre-aggregation)
    float* bufB = (float*)(ws + carve((size_t)n * HIDF * 4));   // h  (post-aggregation)
    (void)ws_size;

    const int nb = (n + 255) / 256;

    detect_i64<<<1, 256, 0, stream>>>((const unsigned int*)ei, flag);

    // gcn_norm
    deg_init<<<nb, 256, 0, stream>>>(dinv, n);
    deg_accum<<<2048, 256, 0, stream>>>(ei, flag, dinv, E);
    deg_to_dinv<<<nb, 256, 0, stream>>>(dinv, n);

    const int gemm_grid = (n + 127) / 128;

    // layer 1
    gemm_k64<INCH><<<gemm_grid, 256, 0, stream>>>(x, W1, bufA, n);
    hipMemsetAsync(bufB, 0, (size_t)n * HIDF * 4, stream);
    scatter_edges<<<4096, 256, 0, stream>>>(bufA, ei, flag, dinv, bufB, E);
    finalize_relu<<<2048, 256, 0, stream>>>(bufB, bufA, dinv, b1, n);

    // layer 2
    gemm_k64<HIDF><<<gemm_grid, 256, 0, stream>>>(bufB, W2, bufA, n);
    hipMemsetAsync(bufB, 0, (size_t)n * HIDF * 4, stream);
    scatter_edges<<<4096, 256, 0, stream>>>(bufA, ei, flag, dinv, bufB, E);
    finalize_relu<<<2048, 256, 0, stream>>>(bufB, bufA, dinv, b2, n);

    // head
    head_kernel<<<gemm_grid, 128, 0, stream>>>(bufB, Wh1, bh1, Wh2, bh2, out, n);
}

// Round 4
// 712.441 us; speedup vs baseline: 2.4876x; 2.4876x over previous
//
#include <hip/hip_runtime.h>

#define NN 100000
#define NE 3200000
#define INCH 256
#define HIDF 64

// ---------------------------------------------------------------------------
// edge dtype sniffer: if edge_index is int64 (values < 2^17), every odd u32
// word is 0. If int32, 256 consecutive odd words all-zero is ~impossible.
// ---------------------------------------------------------------------------
__global__ void detect_i64(const unsigned int* __restrict__ ei, int* __restrict__ flag) {
    __shared__ int nonzero;
    if (threadIdx.x == 0) nonzero = 0;
    __syncthreads();
    if (ei[2 * (size_t)threadIdx.x + 1] != 0u) nonzero = 1;
    __syncthreads();
    if (threadIdx.x == 0) *flag = (nonzero == 0) ? 1 : 0;
}

__device__ __forceinline__ int edge_at(const void* ei, int is64, long long i) {
    if (is64) return (int)((const long long*)ei)[i];
    return ((const int*)ei)[i];
}

// ---------------------------------------------------------------------------
// CSR build: histogram of dst, 3-kernel exclusive scan, bucket scatter
// ---------------------------------------------------------------------------
__global__ void hist_dst(const void* __restrict__ ei, const int* __restrict__ flag,
                         int* __restrict__ cnt, int E) {
    int is64 = *flag;
    long long stride = (long long)gridDim.x * blockDim.x;
    for (long long e = (long long)blockIdx.x * blockDim.x + threadIdx.x; e < E; e += stride) {
        int d = edge_at(ei, is64, (long long)E + e);
        atomicAdd(&cnt[d], 1);
    }
}

__global__ void scan1(const int* __restrict__ cnt, int* __restrict__ blk, int n) {
    __shared__ int sdata[256];
    int i = blockIdx.x * 256 + threadIdx.x;
    int v = (i < n) ? cnt[i] : 0;
    sdata[threadIdx.x] = v;
    __syncthreads();
    for (int s = 128; s > 0; s >>= 1) {
        if (threadIdx.x < s) sdata[threadIdx.x] += sdata[threadIdx.x + s];
        __syncthreads();
    }
    if (threadIdx.x == 0) blk[blockIdx.x] = sdata[0];
}

__global__ void scan2(int* __restrict__ blk, int nb) {   // single block, nb <= 1024
    __shared__ int sdata[1024];
    int t = threadIdx.x;
    int v = (t < nb) ? blk[t] : 0;
    sdata[t] = v;
    __syncthreads();
    for (int off = 1; off < 1024; off <<= 1) {
        int add = (t >= off) ? sdata[t - off] : 0;
        __syncthreads();
        sdata[t] += add;
        __syncthreads();
    }
    if (t < nb) blk[t] = sdata[t] - v;   // exclusive
}

__global__ void scan3(const int* __restrict__ cnt, const int* __restrict__ blk,
                      int* __restrict__ row_start, int n, int E) {
    __shared__ int sdata[256];
    int i = blockIdx.x * 256 + threadIdx.x;
    int v = (i < n) ? cnt[i] : 0;
    sdata[threadIdx.x] = v;
    __syncthreads();
    for (int off = 1; off < 256; off <<= 1) {
        int add = (threadIdx.x >= off) ? sdata[threadIdx.x - off] : 0;
        __syncthreads();
        sdata[threadIdx.x] += add;
        __syncthreads();
    }
    if (i < n) row_start[i] = blk[blockIdx.x] + sdata[threadIdx.x] - v;
    if (i == n - 1) row_start[n] = E;
}

// dinv[i] = rsqrt(indeg+1); also zeroes cnt so it can be reused as the cursor
__global__ void dinv_from_cnt(int* __restrict__ cnt, float* __restrict__ dinv, int n) {
    int i = blockIdx.x * blockDim.x + threadIdx.x;
    if (i < n) {
        dinv[i] = rsqrtf((float)cnt[i] + 1.0f);
        cnt[i] = 0;
    }
}

__global__ void build_csr(const void* __restrict__ ei, const int* __restrict__ flag,
                          const int* __restrict__ row_start, int* __restrict__ cur,
                          int* __restrict__ srcs, int E) {
    int is64 = *flag;
    long long stride = (long long)gridDim.x * blockDim.x;
    for (long long e = (long long)blockIdx.x * blockDim.x + threadIdx.x; e < E; e += stride) {
        int s = edge_at(ei, is64, e);
        int d = edge_at(ei, is64, (long long)E + e);
        int pos = row_start[d] + atomicAdd(&cur[d], 1);
        srcs[pos] = s;
    }
}

// ---------------------------------------------------------------------------
// GEMM: Y[N][64] = dinv[row] * (X[N][K] @ W[K][64])   (scaled epilogue)
// block 256 threads, tile = 128 rows x 64 cols, thread = 8 rows x 4 cols
// ---------------------------------------------------------------------------
template <int K>
__global__ __launch_bounds__(256) void gemm_k64(const float* __restrict__ X,
                                                const float* __restrict__ W,
                                                const float* __restrict__ dinv,
                                                float* __restrict__ Y, int n) {
    __shared__ float xs[128 * 65];
    __shared__ float ws[64 * 64];
    const int t  = threadIdx.x;
    const int r0 = blockIdx.x * 128;
    const int tc = t & 15;
    const int tr = t >> 4;

    float acc[8][4];
#pragma unroll
    for (int i = 0; i < 8; i++)
#pragma unroll
        for (int j = 0; j < 4; j++) acc[i][j] = 0.f;

    for (int kc = 0; kc < K; kc += 64) {
#pragma unroll
        for (int i = 0; i < 4; i++) {
            int off = (i * 256 + t) * 4;
            *(float4*)&ws[off] = *(const float4*)&W[(size_t)kc * 64 + off];
        }
#pragma unroll
        for (int i = 0; i < 8; i++) {
            int linear = i * 256 + t;
            int row = linear >> 4;
            int k4  = linear & 15;
            float4 v = {0.f, 0.f, 0.f, 0.f};
            int gr = r0 + row;
            if (gr < n) v = *(const float4*)&X[(size_t)gr * K + kc + k4 * 4];
            int base = row * 65 + k4 * 4;
            xs[base + 0] = v.x;
            xs[base + 1] = v.y;
            xs[base + 2] = v.z;
            xs[base + 3] = v.w;
        }
        __syncthreads();

#pragma unroll 4
        for (int k = 0; k < 64; k++) {
            float4 wv = *(const float4*)&ws[k * 64 + tc * 4];
#pragma unroll
            for (int i = 0; i < 8; i++) {
                float xv = xs[(tr * 8 + i) * 65 + k];
                acc[i][0] += xv * wv.x;
                acc[i][1] += xv * wv.y;
                acc[i][2] += xv * wv.z;
                acc[i][3] += xv * wv.w;
            }
        }
        __syncthreads();
    }

#pragma unroll
    for (int i = 0; i < 8; i++) {
        int gr = r0 + tr * 8 + i;
        if (gr < n) {
            float s = dinv[gr];
            float4 o = {acc[i][0] * s, acc[i][1] * s, acc[i][2] * s, acc[i][3] * s};
            *(float4*)&Y[(size_t)gr * 64 + tc * 4] = o;
        }
    }
}

// ---------------------------------------------------------------------------
// gather-sum per node: h[d] = relu(dinv[d] * (g[d] + sum_{s in in(d)} g[s]) + b)
// one wave per node, lane = feature; 4 waves per block
// ---------------------------------------------------------------------------
__global__ __launch_bounds__(256) void gather_nodes(const float* __restrict__ g,
                                                    const int* __restrict__ srcs,
                                                    const int* __restrict__ row_start,
                                                    const float* __restrict__ dinv,
                                                    const float* __restrict__ b,
                                                    float* __restrict__ out, int n) {
    int lane = threadIdx.x & 63;
    int node = blockIdx.x * 4 + (threadIdx.x >> 6);
    if (node >= n) return;

    int s0 = row_start[node];
    int s1 = row_start[node + 1];
    float acc = g[(size_t)node * 64 + lane];   // self-loop

    int j = s0;
    for (; j + 4 <= s1; j += 4) {
        int a0 = srcs[j + 0];
        int a1 = srcs[j + 1];
        int a2 = srcs[j + 2];
        int a3 = srcs[j + 3];
        float v0 = g[(size_t)a0 * 64 + lane];
        float v1 = g[(size_t)a1 * 64 + lane];
        float v2 = g[(size_t)a2 * 64 + lane];
        float v3 = g[(size_t)a3 * 64 + lane];
        acc += v0;
        acc += v1;
        acc += v2;
        acc += v3;
    }
    for (; j < s1; j++) acc += g[(size_t)srcs[j] * 64 + lane];

    float v = dinv[node] * acc + b[lane];
    out[(size_t)node * 64 + lane] = fmaxf(v, 0.f);
}

// ---------------------------------------------------------------------------
// fused MLP head: out = relu(h @ Wh1 + bh1) @ Wh2 + bh2
// ---------------------------------------------------------------------------
__global__ __launch_bounds__(128) void head_kernel(const float* __restrict__ h,
                                                   const float* __restrict__ Wh1,
                                                   const float* __restrict__ bh1,
                                                   const float* __restrict__ Wh2,
                                                   const float* __restrict__ bh2,
                                                   float* __restrict__ out, int n) {
    __shared__ float xs[128 * 65];
    __shared__ float w1s[64 * 32];
    __shared__ float w2s[64];
    __shared__ float b1s[32];
    __shared__ float b2s[2];
    const int t  = threadIdx.x;
    const int r0 = blockIdx.x * 128;

#pragma unroll
    for (int i = 0; i < 4; i++) {
        int off = (i * 128 + t) * 4;
        *(float4*)&w1s[off] = *(const float4*)&Wh1[off];
    }
    if (t < 64) w2s[t] = Wh2[t];
    if (t < 32) b1s[t] = bh1[t];
    if (t < 2)  b2s[t] = bh2[t];

#pragma unroll
    for (int i = 0; i < 16; i++) {
        int linear = i * 128 + t;
        int row = linear >> 4;
        int k4  = linear & 15;
        float4 v = {0.f, 0.f, 0.f, 0.f};
        int gr = r0 + row;
        if (gr < n) v = *(const float4*)&h[(size_t)gr * 64 + k4 * 4];
        int base = row * 65 + k4 * 4;
        xs[base + 0] = v.x;
        xs[base + 1] = v.y;
        xs[base + 2] = v.z;
        xs[base + 3] = v.w;
    }
    __syncthreads();

    float hid[32];
#pragma unroll
    for (int j = 0; j < 32; j++) hid[j] = b1s[j];

#pragma unroll 4
    for (int k = 0; k < 64; k++) {
        float xv = xs[t * 65 + k];
#pragma unroll
        for (int j4 = 0; j4 < 8; j4++) {
            float4 w = *(const float4*)&w1s[k * 32 + j4 * 4];
            hid[j4 * 4 + 0] += xv * w.x;
            hid[j4 * 4 + 1] += xv * w.y;
            hid[j4 * 4 + 2] += xv * w.z;
            hid[j4 * 4 + 3] += xv * w.w;
        }
    }

    float o0 = b2s[0], o1 = b2s[1];
#pragma unroll
    for (int j = 0; j < 32; j++) {
        float hv = fmaxf(hid[j], 0.f);
        o0 += hv * w2s[j * 2 + 0];
        o1 += hv * w2s[j * 2 + 1];
    }
    int gr = r0 + t;
    if (gr < n) {
        out[(size_t)gr * 2 + 0] = o0;
        out[(size_t)gr * 2 + 1] = o1;
    }
}

// ---------------------------------------------------------------------------
extern "C" void kernel_launch(void* const* d_in, const int* in_sizes, int n_in,
                              void* d_out, int out_size, void* d_ws, size_t ws_size,
                              hipStream_t stream) {
    const float* x   = (const float*)d_in[0];
    const void*  ei  = d_in[1];
    const float* W1  = (const float*)d_in[2];
    const float* b1  = (const float*)d_in[3];
    const float* W2  = (const float*)d_in[4];
    const float* b2  = (const float*)d_in[5];
    const float* Wh1 = (const float*)d_in[6];
    const float* bh1 = (const float*)d_in[7];
    const float* Wh2 = (const float*)d_in[8];
    const float* bh2 = (const float*)d_in[9];
    float* out = (float*)d_out;

    const int n = in_sizes[0] / INCH;   // 100000
    const int E = in_sizes[1] / 2;      // 3200000

    char* ws = (char*)d_ws;
    size_t off = 0;
    auto carve = [&](size_t bytes) {
        size_t p = off;
        off = (off + bytes + 255) & ~(size_t)255;
        return p;
    };
    int*   flag      = (int*)(ws + carve(256));
    int*   cnt       = (int*)(ws + carve((size_t)n * 4));        // hist -> cursor
    int*   row_start = (int*)(ws + carve((size_t)(n + 1) * 4));
    int*   blk       = (int*)(ws + carve(4096));
    float* dinv      = (float*)(ws + carve((size_t)n * 4));
    int*   srcs      = (int*)(ws + carve((size_t)E * 4));
    float* bufA      = (float*)(ws + carve((size_t)n * HIDF * 4));
    float* bufB      = (float*)(ws + carve((size_t)n * HIDF * 4));
    (void)ws_size;

    const int nb256 = (n + 255) / 256;   // 391 blocks for n=100k

    detect_i64<<<1, 256, 0, stream>>>((const unsigned int*)ei, flag);

    // ---- CSR build + normalization ----
    hipMemsetAsync(cnt, 0, (size_t)n * 4, stream);
    hist_dst<<<2048, 256, 0, stream>>>(ei, flag, cnt, E);
    scan1<<<nb256, 256, 0, stream>>>(cnt, blk, n);
    scan2<<<1, 1024, 0, stream>>>(blk, nb256);
    scan3<<<nb256, 256, 0, stream>>>(cnt, blk, row_start, n, E);
    dinv_from_cnt<<<nb256, 256, 0, stream>>>(cnt, dinv, n);      // also zeroes cnt
    build_csr<<<2048, 256, 0, stream>>>(ei, flag, row_start, cnt, srcs, E);

    const int gemm_grid   = (n + 127) / 128;
    const int gather_grid = (n + 3) / 4;

    // ---- layer 1 ----
    gemm_k64<INCH><<<gemm_grid, 256, 0, stream>>>(x, W1, dinv, bufA, n);
    gather_nodes<<<gather_grid, 256, 0, stream>>>(bufA, srcs, row_start, dinv, b1, bufB, n);

    // ---- layer 2 ----
    gemm_k64<HIDF><<<gemm_grid, 256, 0, stream>>>(bufB, W2, dinv, bufA, n);
    gather_nodes<<<gather_grid, 256, 0, stream>>>(bufA, srcs, row_start, dinv, b2, bufB, n);

    // ---- head ----
    head_kernel<<<gemm_grid, 128, 0, stream>>>(bufB, Wh1, bh1, Wh2, bh2, out, n);
}

// Round 7
// 457.829 us; speedup vs baseline: 3.8710x; 1.5561x over previous
//
#include <hip/hip_runtime.h>

#define INCH 256
#define HIDF 64
#define BSH 8              // 256 nodes per bucket
#define MAXBUCK 512        // supports n up to 131072
#define CHUNK 4096         // edges per bin_records block

// ---------------------------------------------------------------------------
// edge dtype sniffer: if edge_index is int64 (values < 2^17), every odd u32
// word is 0. If int32, 256 consecutive odd words all-zero is ~impossible.
// ---------------------------------------------------------------------------
__global__ void detect_i64(const unsigned int* __restrict__ ei, int* __restrict__ flag) {
    __shared__ int nonzero;
    if (threadIdx.x == 0) nonzero = 0;
    __syncthreads();
    if (ei[2 * (size_t)threadIdx.x + 1] != 0u) nonzero = 1;
    __syncthreads();
    if (threadIdx.x == 0) *flag = (nonzero == 0) ? 1 : 0;
}

__device__ __forceinline__ int edge_at(const void* ei, int is64, long long i) {
    if (is64) return (int)((const long long*)ei)[i];
    return ((const int*)ei)[i];
}

// ---------------------------------------------------------------------------
// pass 1: per-bucket edge counts (LDS histogram, one global add per bucket)
// ---------------------------------------------------------------------------
__global__ __launch_bounds__(256) void bucket_count(const void* __restrict__ ei,
                                                    const int* __restrict__ flag,
                                                    int* __restrict__ bcnt,
                                                    int E, int nbuck) {
    __shared__ int h[MAXBUCK];
    for (int b = threadIdx.x; b < nbuck; b += blockDim.x) h[b] = 0;
    __syncthreads();
    int is64 = *flag;
    long long stride = (long long)gridDim.x * blockDim.x;
    for (long long e = (long long)blockIdx.x * blockDim.x + threadIdx.x; e < E; e += stride) {
        int d = edge_at(ei, is64, (long long)E + e);
        atomicAdd(&h[d >> BSH], 1);
    }
    __syncthreads();
    for (int b = threadIdx.x; b < nbuck; b += blockDim.x)
        if (h[b]) atomicAdd(&bcnt[b], h[b]);
}

// ---------------------------------------------------------------------------
// pass 2: exclusive scan of bucket counts (single block of MAXBUCK threads)
// ---------------------------------------------------------------------------
__global__ void bucket_scan(const int* __restrict__ bcnt, int* __restrict__ bbase,
                            int* __restrict__ bcur, int* __restrict__ row_start,
                            int nbuck, int E, int n) {
    __shared__ int s[MAXBUCK];
    int t = threadIdx.x;
    int v = (t < nbuck) ? bcnt[t] : 0;
    s[t] = v;
    __syncthreads();
    for (int off = 1; off < MAXBUCK; off <<= 1) {
        int add = (t >= off) ? s[t - off] : 0;
        __syncthreads();
        s[t] += add;
        __syncthreads();
    }
    if (t < nbuck) {
        int ex = s[t] - v;
        bbase[t] = ex;
        bcur[t]  = ex;
    }
    if (t == 0) {
        bbase[nbuck] = E;
        row_start[n] = E;
    }
}

// ---------------------------------------------------------------------------
// pass 3: bin (src,dst) records into bucket-contiguous staging.
// One block per 4096-edge chunk: LDS hist -> one global reserve per bucket ->
// records of each bucket land in a contiguous run (L2 coalesces the writeback).
// ---------------------------------------------------------------------------
__global__ __launch_bounds__(256) void bin_records(const void* __restrict__ ei,
                                                   const int* __restrict__ flag,
                                                   int* __restrict__ bcur,
                                                   uint2* __restrict__ staged, int E) {
    __shared__ int cnt[MAXBUCK];
    __shared__ int cur[MAXBUCK];
    const int t = threadIdx.x;
    const int is64 = *flag;
    const long long base = (long long)blockIdx.x * CHUNK;

    for (int b = t; b < MAXBUCK; b += 256) cnt[b] = 0;
    __syncthreads();

    int sr[16], dr[16];
#pragma unroll
    for (int i = 0; i < 16; i++) {
        long long e = base + (long long)i * 256 + t;
        if (e < E) {
            sr[i] = edge_at(ei, is64, e);
            dr[i] = edge_at(ei, is64, (long long)E + e);
            atomicAdd(&cnt[dr[i] >> BSH], 1);
        } else {
            dr[i] = -1;
        }
    }
    __syncthreads();

    for (int b = t; b < MAXBUCK; b += 256)
        if (cnt[b]) cur[b] = atomicAdd(&bcur[b], cnt[b]);
    __syncthreads();

#pragma unroll
    for (int i = 0; i < 16; i++) {
        if (dr[i] >= 0) {
            int gpos = atomicAdd(&cur[dr[i] >> BSH], 1);
            staged[gpos] = make_uint2((unsigned)sr[i], (unsigned)dr[i]);
        }
    }
}

// ---------------------------------------------------------------------------
// pass 4: per bucket (256 nodes): LDS per-node hist + scan -> row_start, dinv,
// then scatter srcs within the bucket's contiguous (L2-resident) region.
// ---------------------------------------------------------------------------
__global__ __launch_bounds__(256) void bucket_finalize(const uint2* __restrict__ staged,
                                                       const int* __restrict__ bbase,
                                                       int* __restrict__ row_start,
                                                       float* __restrict__ dinv,
                                                       int* __restrict__ srcs,
                                                       int n) {
    __shared__ int cnt[256];
    __shared__ int sc[256];
    __shared__ int cur[256];
    const int b  = blockIdx.x;
    const int t  = threadIdx.x;
    const int d0 = b << BSH;
    const int r0 = bbase[b];
    const int r1 = bbase[b + 1];

    cnt[t] = 0;
    __syncthreads();
    for (int j = r0 + t; j < r1; j += 256) {
        uint2 rec = staged[j];
        atomicAdd(&cnt[rec.y - d0], 1);
    }
    __syncthreads();

    int v = cnt[t];
    sc[t] = v;
    __syncthreads();
    for (int off = 1; off < 256; off <<= 1) {
        int add = (t >= off) ? sc[t - off] : 0;
        __syncthreads();
        sc[t] += add;
        __syncthreads();
    }
    int ex = sc[t] - v;

    int node = d0 + t;
    if (node < n) {
        row_start[node] = r0 + ex;
        dinv[node] = rsqrtf((float)v + 1.0f);
    }
    cur[t] = r0 + ex;
    __syncthreads();

    for (int j = r0 + t; j < r1; j += 256) {
        uint2 rec = staged[j];
        int pos = atomicAdd(&cur[rec.y - d0], 1);
        srcs[pos] = (int)rec.x;
    }
}

// ---------------------------------------------------------------------------
// GEMM: Y[N][64] = dinv[row] * (X[N][K] @ W[K][64])   (scaled epilogue)
// block 256 threads, tile = 128 rows x 64 cols, thread = 8 rows x 4 cols
// ---------------------------------------------------------------------------
template <int K>
__global__ __launch_bounds__(256) void gemm_k64(const float* __restrict__ X,
                                                const float* __restrict__ W,
                                                const float* __restrict__ dinv,
                                                float* __restrict__ Y, int n) {
    __shared__ float xs[128 * 65];
    __shared__ float ws[64 * 64];
    const int t  = threadIdx.x;
    const int r0 = blockIdx.x * 128;
    const int tc = t & 15;
    const int tr = t >> 4;

    float acc[8][4];
#pragma unroll
    for (int i = 0; i < 8; i++)
#pragma unroll
        for (int j = 0; j < 4; j++) acc[i][j] = 0.f;

    for (int kc = 0; kc < K; kc += 64) {
#pragma unroll
        for (int i = 0; i < 4; i++) {
            int off = (i * 256 + t) * 4;
            *(float4*)&ws[off] = *(const float4*)&W[(size_t)kc * 64 + off];
        }
#pragma unroll
        for (int i = 0; i < 8; i++) {
            int linear = i * 256 + t;
            int row = linear >> 4;
            int k4  = linear & 15;
            float4 v = {0.f, 0.f, 0.f, 0.f};
            int gr = r0 + row;
            if (gr < n) v = *(const float4*)&X[(size_t)gr * K + kc + k4 * 4];
            int base = row * 65 + k4 * 4;
            xs[base + 0] = v.x;
            xs[base + 1] = v.y;
            xs[base + 2] = v.z;
            xs[base + 3] = v.w;
        }
        __syncthreads();

#pragma unroll 4
        for (int k = 0; k < 64; k++) {
            float4 wv = *(const float4*)&ws[k * 64 + tc * 4];
#pragma unroll
            for (int i = 0; i < 8; i++) {
                float xv = xs[(tr * 8 + i) * 65 + k];
                acc[i][0] += xv * wv.x;
                acc[i][1] += xv * wv.y;
                acc[i][2] += xv * wv.z;
                acc[i][3] += xv * wv.w;
            }
        }
        __syncthreads();
    }

#pragma unroll
    for (int i = 0; i < 8; i++) {
        int gr = r0 + tr * 8 + i;
        if (gr < n) {
            float s = dinv[gr];
            float4 o = {acc[i][0] * s, acc[i][1] * s, acc[i][2] * s, acc[i][3] * s};
            *(float4*)&Y[(size_t)gr * 64 + tc * 4] = o;
        }
    }
}

// ---------------------------------------------------------------------------
// gather-sum per node: h[d] = relu(dinv[d] * (g[d] + sum_{s in in(d)} g[s]) + b)
// one wave per node, lane = feature; 4 waves per block
// ---------------------------------------------------------------------------
__global__ __launch_bounds__(256) void gather_nodes(const float* __restrict__ g,
                                                    const int* __restrict__ srcs,
                                                    const int* __restrict__ row_start,
                                                    const float* __restrict__ dinv,
                                                    const float* __restrict__ b,
                                                    float* __restrict__ out, int n) {
    int lane = threadIdx.x & 63;
    int node = blockIdx.x * 4 + (threadIdx.x >> 6);
    if (node >= n) return;

    int s0 = row_start[node];
    int s1 = row_start[node + 1];
    float acc = g[(size_t)node * 64 + lane];   // self-loop

    int j = s0;
    for (; j + 4 <= s1; j += 4) {
        int a0 = srcs[j + 0];
        int a1 = srcs[j + 1];
        int a2 = srcs[j + 2];
        int a3 = srcs[j + 3];
        float v0 = g[(size_t)a0 * 64 + lane];
        float v1 = g[(size_t)a1 * 64 + lane];
        float v2 = g[(size_t)a2 * 64 + lane];
        float v3 = g[(size_t)a3 * 64 + lane];
        acc += v0;
        acc += v1;
        acc += v2;
        acc += v3;
    }
    for (; j < s1; j++) acc += g[(size_t)srcs[j] * 64 + lane];

    float v = dinv[node] * acc + b[lane];
    out[(size_t)node * 64 + lane] = fmaxf(v, 0.f);
}

// ---------------------------------------------------------------------------
// fused MLP head: out = relu(h @ Wh1 + bh1) @ Wh2 + bh2
// ---------------------------------------------------------------------------
__global__ __launch_bounds__(128) void head_kernel(const float* __restrict__ h,
                                                   const float* __restrict__ Wh1,
                                                   const float* __restrict__ bh1,
                                                   const float* __restrict__ Wh2,
                                                   const float* __restrict__ bh2,
                                                   float* __restrict__ out, int n) {
    __shared__ float xs[128 * 65];
    __shared__ float w1s[64 * 32];
    __shared__ float w2s[64];
    __shared__ float b1s[32];
    __shared__ float b2s[2];
    const int t  = threadIdx.x;
    const int r0 = blockIdx.x * 128;

#pragma unroll
    for (int i = 0; i < 4; i++) {
        int off = (i * 128 + t) * 4;
        *(float4*)&w1s[off] = *(const float4*)&Wh1[off];
    }
    if (t < 64) w2s[t] = Wh2[t];
    if (t < 32) b1s[t] = bh1[t];
    if (t < 2)  b2s[t] = bh2[t];

#pragma unroll
    for (int i = 0; i < 16; i++) {
        int linear = i * 128 + t;
        int row = linear >> 4;
        int k4  = linear & 15;
        float4 v = {0.f, 0.f, 0.f, 0.f};
        int gr = r0 + row;
        if (gr < n) v = *(const float4*)&h[(size_t)gr * 64 + k4 * 4];
        int base = row * 65 + k4 * 4;
        xs[base + 0] = v.x;
        xs[base + 1] = v.y;
        xs[base + 2] = v.z;
        xs[base + 3] = v.w;
    }
    __syncthreads();

    float hid[32];
#pragma unroll
    for (int j = 0; j < 32; j++) hid[j] = b1s[j];

#pragma unroll 4
    for (int k = 0; k < 64; k++) {
        float xv = xs[t * 65 + k];
#pragma unroll
        for (int j4 = 0; j4 < 8; j4++) {
            float4 w = *(const float4*)&w1s[k * 32 + j4 * 4];
            hid[j4 * 4 + 0] += xv * w.x;
            hid[j4 * 4 + 1] += xv * w.y;
            hid[j4 * 4 + 2] += xv * w.z;
            hid[j4 * 4 + 3] += xv * w.w;
        }
    }

    float o0 = b2s[0], o1 = b2s[1];
#pragma unroll
    for (int j = 0; j < 32; j++) {
        float hv = fmaxf(hid[j], 0.f);
        o0 += hv * w2s[j * 2 + 0];
        o1 += hv * w2s[j * 2 + 1];
    }
    int gr = r0 + t;
    if (gr < n) {
        out[(size_t)gr * 2 + 0] = o0;
        out[(size_t)gr * 2 + 1] = o1;
    }
}

// ---------------------------------------------------------------------------
extern "C" void kernel_launch(void* const* d_in, const int* in_sizes, int n_in,
                              void* d_out, int out_size, void* d_ws, size_t ws_size,
                              hipStream_t stream) {
    const float* x   = (const float*)d_in[0];
    const void*  ei  = d_in[1];
    const float* W1  = (const float*)d_in[2];
    const float* b1  = (const float*)d_in[3];
    const float* W2  = (const float*)d_in[4];
    const float* b2  = (const float*)d_in[5];
    const float* Wh1 = (const float*)d_in[6];
    const float* bh1 = (const float*)d_in[7];
    const float* Wh2 = (const float*)d_in[8];
    const float* bh2 = (const float*)d_in[9];
    float* out = (float*)d_out;

    const int n = in_sizes[0] / INCH;   // 100000
    const int E = in_sizes[1] / 2;      // 3200000
    const int nbuck = (n + 255) >> BSH; // 391

    char* ws = (char*)d_ws;
    size_t off = 0;
    auto carve = [&](size_t bytes) {
        size_t p = off;
        off = (off + bytes + 255) & ~(size_t)255;
        return p;
    };
    int*   flag      = (int*)(ws + carve(256));
    int*   bcnt      = (int*)(ws + carve((MAXBUCK + 1) * 4));
    int*   bbase     = (int*)(ws + carve((MAXBUCK + 1) * 4));
    int*   bcur      = (int*)(ws + carve(MAXBUCK * 4));
    int*   row_start = (int*)(ws + carve((size_t)(n + 1) * 4));
    float* dinv      = (float*)(ws + carve((size_t)n * 4));
    int*   srcs      = (int*)(ws + carve((size_t)E * 4));
    float* bufA      = (float*)(ws + carve((size_t)n * HIDF * 4));
    float* bufB      = (float*)(ws + carve((size_t)n * HIDF * 4));
    (void)ws_size;

    // staged (E x 8B = 25.6MB) aliases bufA (n*64*4 = 25.6MB): staged is dead
    // before gemm1 writes bufA.
    uint2* staged = (uint2*)bufA;

    detect_i64<<<1, 256, 0, stream>>>((const unsigned int*)ei, flag);

    // ---- CSR build (bucketed multisplit) ----
    hipMemsetAsync(bcnt, 0, (MAXBUCK + 1) * 4, stream);
    bucket_count<<<1024, 256, 0, stream>>>(ei, flag, bcnt, E, nbuck);
    bucket_scan<<<1, MAXBUCK, 0, stream>>>(bcnt, bbase, bcur, row_start, nbuck, E, n);
    bin_records<<<(E + CHUNK - 1) / CHUNK, 256, 0, stream>>>(ei, flag, bcur, staged, E);
    bucket_finalize<<<nbuck, 256, 0, stream>>>(staged, bbase, row_start, dinv, srcs, n);

    const int gemm_grid   = (n + 127) / 128;
    const int gather_grid = (n + 3) / 4;

    // ---- layer 1 ----
    gemm_k64<INCH><<<gemm_grid, 256, 0, stream>>>(x, W1, dinv, bufA, n);
    gather_nodes<<<gather_grid, 256, 0, stream>>>(bufA, srcs, row_start, dinv, b1, bufB, n);

    // ---- layer 2 ----
    gemm_k64<HIDF><<<gemm_grid, 256, 0, stream>>>(bufB, W2, dinv, bufA, n);
    gather_nodes<<<gather_grid, 256, 0, stream>>>(bufA, srcs, row_start, dinv, b2, bufB, n);

    // ---- head ----
    head_kernel<<<gemm_grid, 128, 0, stream>>>(bufB, Wh1, bh1, Wh2, bh2, out, n);
}